// Round 1
// baseline (90.593 us; speedup 1.0000x reference)
//
#include <hip/hip_runtime.h>
#include <hip/hip_bf16.h>

// LengthRegulator: x [B=32, S=1024, D=384] f32, durations [B,S] int (0..7).
// Output 0: out [B, L, D] f32 where L = max_b sum_t dur[b,t] (derived from out_size).
// Output 1: out_lens [B] (written as float into d_out tail).

#define LR_B 32
#define LR_S 1024
#define LR_D 384           // floats per row = 96 float4
#define LR_V4 (LR_D / 4)   // 96

// Kernel 1: per-batch inclusive cumsum of durations into ws; write out_lens
// (as float) to the tail of d_out.
__global__ __launch_bounds__(LR_S) void lr_cumsum_kernel(
    const int* __restrict__ dur, int* __restrict__ cum,
    float* __restrict__ out_tail) {
  __shared__ int s[LR_S];
  const int b = blockIdx.x;
  const int t = threadIdx.x;
  s[t] = dur[b * LR_S + t];
  __syncthreads();
#pragma unroll
  for (int off = 1; off < LR_S; off <<= 1) {
    int add = (t >= off) ? s[t - off] : 0;
    __syncthreads();
    s[t] += add;
    __syncthreads();
  }
  cum[b * LR_S + t] = s[t];
  if (t == LR_S - 1) out_tail[b] = (float)s[LR_S - 1];
}

// Kernel 2: gather-expand. 192 threads = 2 output rows per block
// (96 float4 lanes per row). One binary search per row, broadcast via LDS.
__global__ __launch_bounds__(192) void lr_gather_kernel(
    const float* __restrict__ x, const int* __restrict__ cum,
    float* __restrict__ out, int L) {
  __shared__ int sidx[2];
  const int tid = threadIdx.x;
  const int sub = tid / LR_V4;       // 0 or 1: which row within the block
  const int v   = tid - sub * LR_V4; // 0..95: float4 index within row
  const int row = blockIdx.x * 2 + sub;  // 0 .. B*L-1 (B*L is even, B=32)

  const int b = row / L;
  const int j = row - b * L;
  const int* __restrict__ c = cum + b * LR_S;

  // One searcher per row: first t with c[t] > j (searchsorted right).
  if (v == 0) {
    const int total = c[LR_S - 1];
    int idx;
    if (j >= total) {
      idx = -1;  // padded tail -> zeros
    } else {
      int lo = 0, hi = LR_S;
      while (lo < hi) {
        int mid = (lo + hi) >> 1;
        if (c[mid] > j) hi = mid; else lo = mid + 1;
      }
      idx = lo;  // < LR_S guaranteed since j < total
    }
    sidx[sub] = idx;
  }
  __syncthreads();

  const int idx = sidx[sub];
  float4* __restrict__ orow =
      (float4*)(out + (size_t)row * LR_D);
  if (idx < 0) {
    orow[v] = make_float4(0.f, 0.f, 0.f, 0.f);
  } else {
    const float4* __restrict__ xrow =
        (const float4*)(x + ((size_t)b * LR_S + idx) * LR_D);
    orow[v] = xrow[v];
  }
}

extern "C" void kernel_launch(void* const* d_in, const int* in_sizes, int n_in,
                              void* d_out, int out_size, void* d_ws, size_t ws_size,
                              hipStream_t stream) {
  const float* x = (const float*)d_in[0];
  const int* dur = (const int*)d_in[1];
  float* out = (float*)d_out;

  // out_size = B*L*D + B  ->  L
  const int L = (out_size - LR_B) / (LR_B * LR_D);

  int* cum = (int*)d_ws;  // B*S ints = 128 KB
  float* out_tail = out + (size_t)LR_B * L * LR_D;

  lr_cumsum_kernel<<<LR_B, LR_S, 0, stream>>>(dur, cum, out_tail);

  const int nrows = LR_B * L;
  lr_gather_kernel<<<nrows / 2, 192, 0, stream>>>(x, cum, out, L);
}

// Round 2
// 48.819 us; speedup vs baseline: 1.8557x; 1.8557x over previous
//
#include <hip/hip_runtime.h>
#include <hip/hip_bf16.h>

// LengthRegulator: x [B=32, S=1024, D=384] f32, durations [B,S] int (0..7).
// Output 0: out [B, L, D] f32 where L = max_b sum_t dur[b,t] (derived from out_size).
// Output 1: out_lens [B] (written as float into d_out tail).
//
// Strategy (round 2): kill the per-row binary search. Build the inverse map
// idx[B*L] by SCATTER inside the cumsum kernel (thread t owns output slots
// [cum[t]-dur, cum[t]) and writes its flattened source row id), pad = -1.
// Gather kernel is then a pure streaming copy with one cached idx load per
// row: latency fully pipelined, write-bandwidth-bound.

#define LR_B 32
#define LR_S 1024
#define LR_D 384           // floats per row = 96 float4
#define LR_V4 (LR_D / 4)   // 96

// Kernel 1: per-batch inclusive cumsum of durations (Hillis-Steele in LDS),
// scatter source-row ids into idx[b*L + j], fill pad with -1, and write
// out_lens (as float) into the tail of d_out.
__global__ __launch_bounds__(LR_S) void lr_build_idx_kernel(
    const int* __restrict__ dur, int* __restrict__ idx,
    float* __restrict__ out_tail, int L) {
  __shared__ int s[LR_S];
  const int b = blockIdx.x;
  const int t = threadIdx.x;
  const int d = dur[b * LR_S + t];
  s[t] = d;
  __syncthreads();
#pragma unroll
  for (int off = 1; off < LR_S; off <<= 1) {
    int add = (t >= off) ? s[t - off] : 0;
    __syncthreads();
    s[t] += add;
    __syncthreads();
  }
  const int end = s[t];          // inclusive cumsum
  const int start = end - d;
  const int total = s[LR_S - 1];

  int* __restrict__ ib = idx + (size_t)b * L;
  const int src = b * LR_S + t;  // flattened source row id
  for (int j = start; j < end; ++j) ib[j] = src;
  // pad tail: [total, L) -> -1
  for (int j = total + t; j < L; j += LR_S) ib[j] = -1;

  if (t == LR_S - 1) out_tail[b] = (float)end;
}

// Kernel 2: pure streaming gather. One thread = one float4 of output.
// gid = row*96 + v, so the output write address is exactly gid (linear).
__global__ __launch_bounds__(256) void lr_gather_kernel(
    const float4* __restrict__ x4, const int* __restrict__ idx,
    float4* __restrict__ out4, int total_v4) {
  const int gid = blockIdx.x * 256 + threadIdx.x;
  if (gid >= total_v4) return;
  const int row = gid / LR_V4;           // compile-time const divisor -> magic mul
  const int v = gid - row * LR_V4;
  const int src = idx[row];              // L2-resident, same value for 96 lanes
  out4[gid] = (src < 0) ? make_float4(0.f, 0.f, 0.f, 0.f)
                        : x4[(size_t)src * LR_V4 + v];
}

extern "C" void kernel_launch(void* const* d_in, const int* in_sizes, int n_in,
                              void* d_out, int out_size, void* d_ws, size_t ws_size,
                              hipStream_t stream) {
  const float* x = (const float*)d_in[0];
  const int* dur = (const int*)d_in[1];
  float* out = (float*)d_out;

  // out_size = B*L*D + B  ->  L
  const int L = (out_size - LR_B) / (LR_B * LR_D);

  int* idx = (int*)d_ws;  // B*L ints (~475 KB for L=3712)
  float* out_tail = out + (size_t)LR_B * L * LR_D;

  lr_build_idx_kernel<<<LR_B, LR_S, 0, stream>>>(dur, idx, out_tail, L);

  const int total_v4 = LR_B * L * LR_V4;
  const int grid = (total_v4 + 255) / 256;
  lr_gather_kernel<<<grid, 256, 0, stream>>>(
      (const float4*)x, idx, (float4*)out, total_v4);
}

// Round 3
// 48.320 us; speedup vs baseline: 1.8749x; 1.0103x over previous
//
#include <hip/hip_runtime.h>
#include <hip/hip_bf16.h>

// LengthRegulator: x [B=32, S=1024, D=384] f32, durations [B,S] int (0..7).
// Output 0: out [B, L, D] f32 where L = max_b sum_t dur[b,t] (derived from out_size).
// Output 1: out_lens [B] (written as float into d_out tail).
//
// Round 3: (a) non-temporal output stores so the 182 MB write stream doesn't
// evict x (50 MB) from L3 between graph replays -> kills the ~54 MB HBM
// re-fetch; (b) shfl-based scan in kernel 1 (2 barriers instead of 20).

#define LR_B 32
#define LR_S 1024
#define LR_D 384           // floats per row = 96 float4
#define LR_V4 (LR_D / 4)   // 96

typedef float f32x4 __attribute__((ext_vector_type(4)));

// Kernel 1: per-batch inclusive cumsum of durations (wave shfl scan + one
// cross-wave pass), scatter flattened source-row ids into idx[b*L + j],
// fill pad with -1, write out_lens (as float) into the tail of d_out.
__global__ __launch_bounds__(LR_S) void lr_build_idx_kernel(
    const int* __restrict__ dur, int* __restrict__ idx,
    float* __restrict__ out_tail, int L) {
  __shared__ int wsum[LR_S / 64];  // 16 wave totals
  const int b = blockIdx.x;
  const int t = threadIdx.x;
  const int wave = t >> 6;
  const int lane = t & 63;
  const int d = dur[b * LR_S + t];

  // wave-level inclusive scan (no barriers)
  int v = d;
#pragma unroll
  for (int off = 1; off < 64; off <<= 1) {
    int n = __shfl_up(v, off, 64);
    if (lane >= off) v += n;
  }
  if (lane == 63) wsum[wave] = v;
  __syncthreads();

  // per-thread prefix over wave totals (16 broadcast LDS reads)
  int woff = 0, tot = 0;
#pragma unroll
  for (int w = 0; w < LR_S / 64; ++w) {
    int s = wsum[w];
    if (w < wave) woff += s;
    tot += s;
  }
  const int end = woff + v;      // inclusive cumsum of this thread
  const int start = end - d;

  int* __restrict__ ib = idx + (size_t)b * L;
  const int src = b * LR_S + t;  // flattened source row id
  for (int j = start; j < end; ++j) ib[j] = src;
  for (int j = tot + t; j < L; j += LR_S) ib[j] = -1;  // pad tail

  if (t == 0) out_tail[b] = (float)tot;
}

// Kernel 2: pure streaming gather. One thread = one float4 of output.
// Output store is non-temporal: keep x resident in L2/L3 across replays.
__global__ __launch_bounds__(256) void lr_gather_kernel(
    const f32x4* __restrict__ x4, const int* __restrict__ idx,
    f32x4* __restrict__ out4, int total_v4) {
  const int gid = blockIdx.x * 256 + threadIdx.x;
  if (gid >= total_v4) return;
  const int row = gid / LR_V4;           // const divisor -> magic mul
  const int v = gid - row * LR_V4;
  const int src = idx[row];              // L2-resident, shared by 96 lanes
  f32x4 val;
  if (src < 0) {
    val = (f32x4){0.f, 0.f, 0.f, 0.f};
  } else {
    val = x4[(size_t)src * LR_V4 + v];
  }
  __builtin_nontemporal_store(val, &out4[gid]);
}

extern "C" void kernel_launch(void* const* d_in, const int* in_sizes, int n_in,
                              void* d_out, int out_size, void* d_ws, size_t ws_size,
                              hipStream_t stream) {
  const float* x = (const float*)d_in[0];
  const int* dur = (const int*)d_in[1];
  float* out = (float*)d_out;

  // out_size = B*L*D + B  ->  L
  const int L = (out_size - LR_B) / (LR_B * LR_D);

  int* idx = (int*)d_ws;  // B*L ints (~475 KB for L=3712)
  float* out_tail = out + (size_t)LR_B * L * LR_D;

  lr_build_idx_kernel<<<LR_B, LR_S, 0, stream>>>(dur, idx, out_tail, L);

  const int total_v4 = LR_B * L * LR_V4;
  const int grid = (total_v4 + 255) / 256;
  lr_gather_kernel<<<grid, 256, 0, stream>>>(
      (const f32x4*)x, idx, (f32x4*)out, total_v4);
}

// Round 4
// 40.831 us; speedup vs baseline: 2.2188x; 1.1834x over previous
//
#include <hip/hip_runtime.h>
#include <hip/hip_bf16.h>

// LengthRegulator: x [B=32, S=1024, D=384] f32, durations [B,S] int (0..7).
// Output 0: out [B, L, D] f32, L = max_b sum_t dur[b,t] (derived from out_size).
// Output 1: out_lens [B] (float, tail of d_out).
//
// Round 4: single fused kernel. Each block redundantly scans its batch's
// durations (4 KB, L2-resident; int4 loads + wave shfl scan), builds the
// inverse map for its own 32-row output chunk in LDS by scatter, then
// stream-copies the chunk. No idx table, no second launch, no 32-block
// serial front-end.

#define LR_B 32
#define LR_S 1024
#define LR_D 384           // floats per row = 96 float4
#define LR_V4 (LR_D / 4)   // 96
#define ROWS_PB 32         // output rows per block

typedef float f32x4 __attribute__((ext_vector_type(4)));

__global__ __launch_bounds__(256) void lr_fused_kernel(
    const f32x4* __restrict__ x4, const int* __restrict__ dur,
    f32x4* __restrict__ out4, float* __restrict__ out_tail, int L) {
  __shared__ int wsum[4];        // 4 wave totals (256 threads)
  __shared__ int lidx[ROWS_PB];  // source step per output row in this chunk
  const int b = blockIdx.y;
  const int r0 = blockIdx.x * ROWS_PB;
  const int t = threadIdx.x;
  const int wave = t >> 6, lane = t & 63;

  // ---- per-batch cumsum (redundant per block; 4 KB, L2-hit) ----
  const int4 d4 = ((const int4*)(dur + b * LR_S))[t];  // elems [4t, 4t+4)
  const int e0 = d4.x, e1 = e0 + d4.y, e2 = e1 + d4.z, e3 = e2 + d4.w;
  int v = e3;
#pragma unroll
  for (int off = 1; off < 64; off <<= 1) {
    int n = __shfl_up(v, off, 64);
    if (lane >= off) v += n;
  }
  if (lane == 63) wsum[wave] = v;
  if (t < ROWS_PB) lidx[t] = -1;
  __syncthreads();

  int woff = 0, tot = 0;
#pragma unroll
  for (int w = 0; w < 4; ++w) {
    int s = wsum[w];
    if (w < wave) woff += s;
    tot += s;
  }
  const int base = woff + v - e3;  // exclusive prefix of this thread's 4 elems

  // ---- scatter inverse map for rows [r0, r0+ROWS_PB) ----
  const int r1 = min(r0 + ROWS_PB, L);
  const int starts[4] = {base, base + e0, base + e1, base + e2};
  const int ends[4]   = {base + e0, base + e1, base + e2, base + e3};
#pragma unroll
  for (int k = 0; k < 4; ++k) {
    const int s = max(starts[k], r0), e = min(ends[k], r1);
    for (int j = s; j < e; ++j) lidx[j - r0] = t * 4 + k;
  }
  __syncthreads();

  // ---- stream-copy the chunk: ROWS_PB rows x 96 float4 ----
  const size_t obase = ((size_t)b * L + r0) * LR_V4;
  const size_t xbase = (size_t)b * LR_S * LR_V4;
#pragma unroll
  for (int i = 0; i < ROWS_PB * LR_V4 / 256; ++i) {
    const int p = i * 256 + t;        // 0 .. ROWS_PB*96-1
    const int r = p / LR_V4;          // const divisor -> magic mul
    const int vv = p - r * LR_V4;
    if (r0 + r >= L) continue;        // tail-chunk guard
    const int st = lidx[r];
    f32x4 val = (st < 0) ? (f32x4){0.f, 0.f, 0.f, 0.f}
                         : x4[xbase + (size_t)st * LR_V4 + vv];
    __builtin_nontemporal_store(val, &out4[obase + p]);
  }

  if (blockIdx.x == 0 && t == 0) out_tail[b] = (float)tot;
}

extern "C" void kernel_launch(void* const* d_in, const int* in_sizes, int n_in,
                              void* d_out, int out_size, void* d_ws, size_t ws_size,
                              hipStream_t stream) {
  const float* x = (const float*)d_in[0];
  const int* dur = (const int*)d_in[1];
  float* out = (float*)d_out;

  // out_size = B*L*D + B  ->  L
  const int L = (out_size - LR_B) / (LR_B * LR_D);
  float* out_tail = out + (size_t)LR_B * L * LR_D;

  const int nchunks = (L + ROWS_PB - 1) / ROWS_PB;
  dim3 grid(nchunks, LR_B);
  lr_fused_kernel<<<grid, 256, 0, stream>>>(
      (const f32x4*)x, dur, (f32x4*)out, out_tail, L);
}